// Round 8
// baseline (239.414 us; speedup 1.0000x reference)
//
#include <hip/hip_runtime.h>
#include <stdint.h>

// MultiHeadAttention: B=8, N=1024 (32x32 tokens), E=1024, H=16, D=64.
// Pipeline: prep(cvt x/wqkv/wout + f32 bias table) -> gemm_qkv -> attn -> gemm_out.
// All GEMM-shaped compute on v_mfma_f32_16x16x32_bf16 (fp32 accum).
// Fragment maps (learn_hip m89/m91/m120):
//   A: lane holds A[m=lane&15][k=8*(lane>>4)+t]
//   B: lane holds B[k=8*(lane>>4)+t][n=lane&15]
//   C/D: col=lane&15, row=4*(lane>>4)+reg
// R8: softmax reduced to exp2+pack only: (a) compact bias table stored f32
// (2MB, L2-resident) and used as the MFMA C-operand init -> bias add runs on
// the matrix pipe; (b) Q pre-scaled by 0.125*log2e in the gemm_qkv epilogue
// (same bf16 rounding count -> identical error class); (c) gemm0 Q/K epilogue
// branch made block-uniform. R7 keepers: 48KB LDS/3 blocks/CU, 3 barriers/js,
// conflict-free P subchunk layout, ones-column MFMA row sums, register Q.

#define LOG2E 1.4426950408889634f
#define SCLQ (0.125f * LOG2E)

typedef __attribute__((ext_vector_type(8))) short short8;
typedef __attribute__((ext_vector_type(4))) short short4v;
typedef __attribute__((ext_vector_type(4))) float floatx4;
typedef __attribute__((ext_vector_type(2))) unsigned int uint2v;

__device__ __forceinline__ short f2bf(float f) {  // RNE, matches HW/numpy
  uint32_t u = __builtin_bit_cast(uint32_t, f);
  u = (u + 0x7FFFu + ((u >> 16) & 1u)) >> 16;
  return (short)(uint16_t)u;
}
__device__ __forceinline__ float fast_exp2(float x) {
#if __has_builtin(__builtin_amdgcn_exp2f)
  return __builtin_amdgcn_exp2f(x);
#else
  return exp2f(x);
#endif
}

__device__ __forceinline__ void gload_lds16(const short* g, short* l) {
  __builtin_amdgcn_global_load_lds(
      (const __attribute__((address_space(1))) void*)g,
      (__attribute__((address_space(3))) void*)l, 16, 0, 0);
}

// ---------------- fused prep: fp32->bf16 converts + f32 bias table --------
// blocks [0,8192): x ; [8192,11264): w_qkv ; [11264,12288): w_out ;
// [12288,13312): bias tiles.
// Bias tile T[h][dra][ap][bp][lane][r] = biases[h][dra*32+|16ap+4qd+r-(16bp+col)|]
// * LOG2E (f32). Valid because RES=32 and tiles 16-aligned: for
// j=32*ar+16*ap+4qd+r, rj=ar and cj=16ap+4qd+r exactly (no carry).
__global__ void prep(const float* __restrict__ x, const float* __restrict__ wqkv,
                     const float* __restrict__ wout, const float* __restrict__ biases,
                     short* __restrict__ xb, short* __restrict__ wqkvb,
                     short* __restrict__ woutb, float* __restrict__ biast) {
  int blk = blockIdx.x, tid = threadIdx.x;
  if (blk < 12288) {
    const float* src;
    short* dst;
    int i;
    if (blk < 8192) { src = x; dst = xb; i = blk * 256 + tid; }
    else if (blk < 11264) { src = wqkv; dst = wqkvb; i = (blk - 8192) * 256 + tid; }
    else { src = wout; dst = woutb; i = (blk - 11264) * 256 + tid; }
    float4 f = ((const float4*)src)[i];
    short4v o;
    o.x = f2bf(f.x); o.y = f2bf(f.y); o.z = f2bf(f.z); o.w = f2bf(f.w);
    ((short4v*)dst)[i] = o;
  } else {
    int tile = (blk - 12288) * 4 + (tid >> 6);  // [0, 4096)
    int lane = tid & 63, qd = lane >> 4, col = lane & 15;
    int bp = tile & 1, ap = (tile >> 1) & 1, dra = (tile >> 2) & 31, h = tile >> 7;
    int ci = 16 * bp + col;
    floatx4 o;
#pragma unroll
    for (int r = 0; r < 4; r++) {
      int cj = 16 * ap + 4 * qd + r;
      int dc = cj - ci; if (dc < 0) dc = -dc;
      o[r] = biases[h * 1024 + dra * 32 + dc] * LOG2E;
    }
    *(floatx4*)&biast[(size_t)tile * 256 + lane * 4] = o;
  }
}

// ---------------- 128x128 tile GEMM, C = A @ Bt^T ------------------
// A [M][1024] bf16 row-major, Bt [N][1024] bf16 row-major (= B transposed).
// MODE 0: QKV epilogue (Q pre-scaled by SCLQ; q,k [bh][n][64], vt [bh][64][n])
// MODE 1: out-proj epilogue (add bvec, fp32 store)
template <int MODE>
__global__ __launch_bounds__(256, 2) void gemm_bt(
    const short* __restrict__ A, const short* __restrict__ Bt,
    short* __restrict__ qo, short* __restrict__ ko, short* __restrict__ vto,
    const float* __restrict__ bvec, float* __restrict__ outf) {
  __shared__ __align__(16) short sA[128 * 64];
  __shared__ __align__(16) short sB[128 * 64];
  const int tid = threadIdx.x;
  const int w = tid >> 6, lane = tid & 63;
  const int wr = w >> 1, wc = w & 1;
  const int bm = blockIdx.y, bn = blockIdx.x;
  const int qd = lane >> 4, col = lane & 15;

  floatx4 acc[4][4] = {};
  const int rowA0 = bm * 128, rowB0 = bn * 128;
  const int ciw = w * 256;

  for (int kk = 0; kk < 1024; kk += 64) {
    __syncthreads();
#pragma unroll
    for (int n = 0; n < 4; n++) {
      int ci = ciw + n * 64 + lane;
      int r = ci >> 3, c = (ci & 7) ^ (r & 7);
      gload_lds16(A + (size_t)(rowA0 + r) * 1024 + kk + c * 8, &sA[ci * 8]);
    }
#pragma unroll
    for (int n = 0; n < 4; n++) {
      int ci = ciw + n * 64 + lane;
      int r = ci >> 3, c = (ci & 7) ^ (r & 7);
      gload_lds16(Bt + (size_t)(rowB0 + r) * 1024 + kk + c * 8, &sB[ci * 8]);
    }
    __syncthreads();

#pragma unroll
    for (int ks = 0; ks < 2; ks++) {
      const int ch = qd + ks * 4;
      short8 af[4], bff[4];
#pragma unroll
      for (int rt = 0; rt < 4; rt++) {
        int r = wr * 64 + rt * 16 + col;
        af[rt] = *(const short8*)&sA[r * 64 + ((ch ^ (r & 7)) << 3)];
      }
#pragma unroll
      for (int ct = 0; ct < 4; ct++) {
        int r = wc * 64 + ct * 16 + col;
        bff[ct] = *(const short8*)&sB[r * 64 + ((ch ^ (r & 7)) << 3)];
      }
#pragma unroll
      for (int rt = 0; rt < 4; rt++)
#pragma unroll
        for (int ct = 0; ct < 4; ct++)
          acc[rt][ct] = __builtin_amdgcn_mfma_f32_16x16x32_bf16(af[rt], bff[ct], acc[rt][ct], 0, 0, 0);
    }
  }

  if (MODE == 0) {
    if (bn >= 16) {
      // V region (block-uniform): pack 4 consecutive n into b64 scatters
#pragma unroll
      for (int rt = 0; rt < 4; rt++) {
#pragma unroll
        for (int ct = 0; ct < 4; ct++) {
          int Cg = bn * 128 + wc * 64 + ct * 16 + col;
          int e = Cg & 1023, h = e >> 6, dd = e & 63;
          short4v pv;
#pragma unroll
          for (int r = 0; r < 4; r++) pv[r] = f2bf(acc[rt][ct][r]);
          int R0 = bm * 128 + wr * 64 + rt * 16 + qd * 4;
          int b = R0 >> 10, n0 = R0 & 1023;
          int bh = b * 16 + h;
          *(short4v*)&vto[((size_t)bh * 64 + dd) * 1024 + n0] = pv;
        }
      }
    } else {
      // Q (bn<8, pre-scaled by SCLQ) or K region; block-uniform choice
      short* dst = (bn < 8) ? qo : ko;
      const float qscl = (bn < 8) ? SCLQ : 1.0f;
#pragma unroll
      for (int rt = 0; rt < 4; rt++) {
#pragma unroll
        for (int ct = 0; ct < 4; ct++) {
          int Cg = bn * 128 + wc * 64 + ct * 16 + col;
          int e = Cg & 1023, h = e >> 6, dd = e & 63;
#pragma unroll
          for (int r = 0; r < 4; r++) {
            int R = bm * 128 + wr * 64 + rt * 16 + qd * 4 + r;
            int b = R >> 10, n = R & 1023;
            int bh = b * 16 + h;
            dst[((size_t)bh * 1024 + n) * 64 + dd] = f2bf(acc[rt][ct][r] * qscl);
          }
        }
      }
    }
  } else {
#pragma unroll
    for (int rt = 0; rt < 4; rt++)
#pragma unroll
      for (int ct = 0; ct < 4; ct++) {
        int Cg = bn * 128 + wc * 64 + ct * 16 + col;
        float bo = bvec[Cg];
#pragma unroll
        for (int r = 0; r < 4; r++) {
          int R = bm * 128 + wr * 64 + rt * 16 + qd * 4 + r;
          outf[(size_t)R * 1024 + Cg] = acc[rt][ct][r] + bo;
        }
      }
  }
}

// ---------------- fused attention (flash-style, no max: logits bounded) ----
// grid.x = bh (128), grid.y = qt (16). Per block: Q-tile 64 rows; 8 K/V tiles
// of 128. S^T = K Q'^T + bias (bias = MFMA C-init, f32; Q pre-scaled).
// LDS: sK 16KB (XOR-8), sVt 16KB (XOR-16), sP 16KB (subchunk layout; Q
// staging temp at start). 48KB -> 3 blocks/CU. 3 barriers per js.
__global__ __launch_bounds__(256, 3) void attn_fused(
    const short* __restrict__ q, const short* __restrict__ k,
    const short* __restrict__ vt, const float* __restrict__ biast,
    short* __restrict__ ao) {
  __shared__ __align__(16) short sK[128 * 64];
  __shared__ __align__(16) short sVt[64 * 128];
  __shared__ __align__(16) short sP[64 * 128];
  const int tid = threadIdx.x, w = tid >> 6, lane = tid & 63;
  const int bh = blockIdx.x, qt = blockIdx.y;
  const int h = bh & 15;
  const int qd = lane >> 4, col = lane & 15;
  const short* qb = q + (size_t)bh * 65536;
  const short* kb = k + (size_t)bh * 65536;
  const short* vb = vt + (size_t)bh * 65536;
  const int ciw = w * 256;

  // stage Q tile (64 rows at qt*64) into sP temp, XOR-8, hoist to regs
#pragma unroll
  for (int n = 0; n < 2; n++) {
    int ci = w * 128 + n * 64 + lane;
    int r = ci >> 3, c = (ci & 7) ^ (r & 7);
    gload_lds16(qb + (size_t)(qt * 64 + r) * 64 + c * 8, &sP[ci * 8]);
  }
  __syncthreads();
  short8 bq[2][4];  // [ks][ct] B-frags of Q, js-invariant (32 VGPRs)
#pragma unroll
  for (int ks = 0; ks < 2; ks++) {
    const int ch = qd + ks * 4;
#pragma unroll
    for (int ct = 0; ct < 4; ct++) {
      int r2 = ct * 16 + col;
      bq[ks][ct] = *(const short8*)&sP[r2 * 64 + ((ch ^ (r2 & 7)) << 3)];
    }
  }

  // ones B-frag for row-sum MFMA (bf16 1.0 = 0x3F80)
  short8 onesf;
#pragma unroll
  for (int t = 0; t < 8; t++) onesf[t] = (short)0x3F80;

  floatx4 oacc[4] = {};  // [d-tile ct], O rows i in [16w,16w+16)
  floatx4 osum = {};

  for (int js = 0; js < 8; js++) {
    __syncthreads();  // B1: prior PV reads done (js=0: Q-frag reads done)
    // stage K tile [128][64] into sK, XOR-8
#pragma unroll
    for (int n = 0; n < 4; n++) {
      int ci = ciw + n * 64 + lane;
      int r = ci >> 3, c = (ci & 7) ^ (r & 7);
      gload_lds16(kb + (size_t)(js * 128 + r) * 64 + c * 8, &sK[ci * 8]);
    }
    // stage Vt tile [64][128] into sVt, XOR-16
#pragma unroll
    for (int n = 0; n < 4; n++) {
      int ci = ciw + n * 64 + lane;
      int r = ci >> 4, c = (ci & 15) ^ (r & 15);
      gload_lds16(vb + (size_t)r * 1024 + js * 128 + c * 8, &sVt[ci * 8]);
    }
    __syncthreads();  // B2: staged

    // S^T tiles (wave w: j rows [32w,32w+32), i cols 0..64): C-init = bias,
    // then softmax is exp2 + pack only.
#pragma unroll
    for (int rt = 0; rt < 2; rt++) {
      const int a = js * 8 + w * 2 + rt;    // global j-tile
      const int s = w * 8 + rt * 4 + qd;    // P subchunk index (j>>2)
      const int ar = a >> 1, apar = a & 1;
      floatx4 sacc[4];
#pragma unroll
      for (int ct = 0; ct < 4; ct++) {      // C-init = f32 bias fragment
        int b = qt * 4 + ct;                 // global i-tile
        int dra = ar - (b >> 1); if (dra < 0) dra = -dra;
        int tile = ((h * 32 + dra) * 2 + apar) * 2 + (b & 1);
        sacc[ct] = *(const floatx4*)&biast[(size_t)tile * 256 + lane * 4];
      }
      const int r = w * 32 + rt * 16 + col;
      short8 ak0 = *(const short8*)&sK[r * 64 + (((qd + 0) ^ (r & 7)) << 3)];
      short8 ak1 = *(const short8*)&sK[r * 64 + (((qd + 4) ^ (r & 7)) << 3)];
#pragma unroll
      for (int ct = 0; ct < 4; ct++)
        sacc[ct] = __builtin_amdgcn_mfma_f32_16x16x32_bf16(ak0, bq[0][ct], sacc[ct], 0, 0, 0);
#pragma unroll
      for (int ct = 0; ct < 4; ct++)
        sacc[ct] = __builtin_amdgcn_mfma_f32_16x16x32_bf16(ak1, bq[1][ct], sacc[ct], 0, 0, 0);
#pragma unroll
      for (int ct = 0; ct < 4; ct++) {
        int i = ct * 16 + col;  // local i in [0,64)
        float e0 = fast_exp2(sacc[ct][0]);
        float e1 = fast_exp2(sacc[ct][1]);
        float e2 = fast_exp2(sacc[ct][2]);
        float e3 = fast_exp2(sacc[ct][3]);
        uint32_t u0 = __builtin_bit_cast(uint32_t, e0) + 0x8000u;
        uint32_t u1 = __builtin_bit_cast(uint32_t, e1) + 0x8000u;
        uint32_t u2 = __builtin_bit_cast(uint32_t, e2) + 0x8000u;
        uint32_t u3 = __builtin_bit_cast(uint32_t, e3) + 0x8000u;
        uint2v pk;
        pk.x = __builtin_amdgcn_perm(u1, u0, 0x07060302u);  // [bf(e1):bf(e0)]
        pk.y = __builtin_amdgcn_perm(u3, u2, 0x07060302u);  // [bf(e3):bf(e2)]
        *(uint2v*)&sP[i * 128 + ((s ^ (i & 15)) << 2)] = pk;  // conflict-free
      }
    }
    __syncthreads();  // B3: P visible cross-wave

    // O += P @ V ; osum += P @ 1. Wave w: O rows i in [16w,16w+16).
#pragma unroll
    for (int ks = 0; ks < 4; ks++) {
      const int ch = ks * 4 + qd;
      int m = w * 16 + col;
      short4v lo = *(const short4v*)&sP[m * 128 + (((2 * ch) ^ col) << 2)];
      short4v hi = *(const short4v*)&sP[m * 128 + (((2 * ch + 1) ^ col) << 2)];
      short8 ap = __builtin_shufflevector(lo, hi, 0, 1, 2, 3, 4, 5, 6, 7);
      short8 bv[4];
#pragma unroll
      for (int ct = 0; ct < 4; ct++) {
        int d = ct * 16 + col;
        bv[ct] = *(const short8*)&sVt[d * 128 + ((ch ^ (d & 15)) << 3)];
      }
#pragma unroll
      for (int ct = 0; ct < 4; ct++)
        oacc[ct] = __builtin_amdgcn_mfma_f32_16x16x32_bf16(ap, bv[ct], oacc[ct], 0, 0, 0);
      osum = __builtin_amdgcn_mfma_f32_16x16x32_bf16(ap, onesf, osum, 0, 0, 0);
    }
  }

  // write O as attn_out [b][n][h*64+dd] bf16 ; denominator from osum
  const int b = bh >> 4;
  floatx4 inv;
#pragma unroll
  for (int r = 0; r < 4; r++) inv[r] = 1.0f / osum[r];
#pragma unroll
  for (int ct = 0; ct < 4; ct++)
#pragma unroll
    for (int r = 0; r < 4; r++) {
      int n = qt * 64 + w * 16 + qd * 4 + r;
      int dd = ct * 16 + col;
      ao[(((size_t)b * 1024 + n) << 10) + h * 64 + dd] = f2bf(oacc[ct][r] * inv[r]);
    }
}

// -------------------------------------------------------------------
extern "C" void kernel_launch(void* const* d_in, const int* in_sizes, int n_in,
                              void* d_out, int out_size, void* d_ws, size_t ws_size,
                              hipStream_t stream) {
  const float* x = (const float*)d_in[0];       // [8,1024,1024]
  const float* w_qkv = (const float*)d_in[1];   // [3072,1024]
  const float* biases = (const float*)d_in[2];  // [16,1024]
  // d_in[3] bias_idxs unused: index formula is closed-form
  const float* w_out = (const float*)d_in[4];   // [1024,1024]
  const float* b_out = (const float*)d_in[5];   // [1024]
  float* out = (float*)d_out;

  char* ws = (char*)d_ws;
  short* xb    = (short*)(ws + 0);          // 16 MB  [8192][1024]
  short* wqkvb = (short*)(ws + 16777216);   // 6 MB   [3072][1024]
  short* woutb = (short*)(ws + 23068672);   // 2 MB   [1024][1024]
  short* qb    = (short*)(ws + 25165824);   // 16 MB  [128 bh][1024][64]
  short* kb    = (short*)(ws + 41943040);   // 16 MB
  short* vtb   = (short*)(ws + 58720256);   // 16 MB  [128 bh][64][1024]
  short* aob   = (short*)(ws + 75497472);   // 16 MB  [8192][1024]
  float* biast = (float*)(ws + 92274688);   // 2 MB   [16][32][2][2][64][4] f32

  prep<<<13312, 256, 0, stream>>>(x, w_qkv, w_out, biases, xb, wqkvb, woutb, biast);
  gemm_bt<0><<<dim3(24, 64), 256, 0, stream>>>(xb, wqkvb, qb, kb, vtb, nullptr, nullptr);
  attn_fused<<<dim3(128, 16), 256, 0, stream>>>(qb, kb, vtb, biast, aob);
  gemm_bt<1><<<dim3(8, 64), 256, 0, stream>>>(aob, woutb, nullptr, nullptr, nullptr, b_out, out);
}

// Round 9
// 238.281 us; speedup vs baseline: 1.0048x; 1.0048x over previous
//
#include <hip/hip_runtime.h>
#include <stdint.h>

// MultiHeadAttention: B=8, N=1024 (32x32 tokens), E=1024, H=16, D=64.
// Pipeline: prep(cvt x/wqkv/wout + f32 bias table) -> gemm_qkv -> attn -> gemm_out.
// All GEMM-shaped compute on v_mfma_f32_16x16x32_bf16 (fp32 accum).
// Fragment maps (learn_hip m89/m91/m120):
//   A: lane holds A[m=lane&15][k=8*(lane>>4)+t]
//   B: lane holds B[k=8*(lane>>4)+t][n=lane&15]
//   C/D: col=lane&15, row=4*(lane>>4)+reg
// R9 attn: register-staged K/V prefetch (AITER pattern). R8 showed the loop is
// stall-bound: global_load_lds forces s_waitcnt vmcnt(0) at the staging
// barrier, exposing full HBM/L2 latency 8x/block. Now K/V[js+1] are loaded to
// VGPRs during js's S+PV phases (plain loads need no vmcnt drain at barriers)
// and committed via ds_write_b128 at the top of js+1; only lgkmcnt is drained
// at B2. LDS stays 48KB -> 3 blocks/CU (R6's LDS dbuf lost TLP; this doesn't).
// Keepers: f32 bias as MFMA C-init, pre-scaled Q, conflict-free P subchunk
// layout, ones-column MFMA row sums, register-resident Q frags.

#define LOG2E 1.4426950408889634f
#define SCLQ (0.125f * LOG2E)

typedef __attribute__((ext_vector_type(8))) short short8;
typedef __attribute__((ext_vector_type(4))) short short4v;
typedef __attribute__((ext_vector_type(4))) float floatx4;
typedef __attribute__((ext_vector_type(2))) unsigned int uint2v;
typedef __attribute__((ext_vector_type(4))) unsigned int uint4v;

__device__ __forceinline__ short f2bf(float f) {  // RNE, matches HW/numpy
  uint32_t u = __builtin_bit_cast(uint32_t, f);
  u = (u + 0x7FFFu + ((u >> 16) & 1u)) >> 16;
  return (short)(uint16_t)u;
}
__device__ __forceinline__ float fast_exp2(float x) {
#if __has_builtin(__builtin_amdgcn_exp2f)
  return __builtin_amdgcn_exp2f(x);
#else
  return exp2f(x);
#endif
}

__device__ __forceinline__ void gload_lds16(const short* g, short* l) {
  __builtin_amdgcn_global_load_lds(
      (const __attribute__((address_space(1))) void*)g,
      (__attribute__((address_space(3))) void*)l, 16, 0, 0);
}

// ---------------- fused prep: fp32->bf16 converts + f32 bias table --------
// blocks [0,8192): x ; [8192,11264): w_qkv ; [11264,12288): w_out ;
// [12288,13312): bias tiles.
// Bias tile T[h][dra][ap][bp][lane][r] = biases[h][dra*32+|16ap+4qd+r-(16bp+col)|]
// * LOG2E (f32). Valid because RES=32 and tiles 16-aligned: for
// j=32*ar+16*ap+4qd+r, rj=ar and cj=16ap+4qd+r exactly (no carry).
__global__ void prep(const float* __restrict__ x, const float* __restrict__ wqkv,
                     const float* __restrict__ wout, const float* __restrict__ biases,
                     short* __restrict__ xb, short* __restrict__ wqkvb,
                     short* __restrict__ woutb, float* __restrict__ biast) {
  int blk = blockIdx.x, tid = threadIdx.x;
  if (blk < 12288) {
    const float* src;
    short* dst;
    int i;
    if (blk < 8192) { src = x; dst = xb; i = blk * 256 + tid; }
    else if (blk < 11264) { src = wqkv; dst = wqkvb; i = (blk - 8192) * 256 + tid; }
    else { src = wout; dst = woutb; i = (blk - 11264) * 256 + tid; }
    float4 f = ((const float4*)src)[i];
    short4v o;
    o.x = f2bf(f.x); o.y = f2bf(f.y); o.z = f2bf(f.z); o.w = f2bf(f.w);
    ((short4v*)dst)[i] = o;
  } else {
    int tile = (blk - 12288) * 4 + (tid >> 6);  // [0, 4096)
    int lane = tid & 63, qd = lane >> 4, col = lane & 15;
    int bp = tile & 1, ap = (tile >> 1) & 1, dra = (tile >> 2) & 31, h = tile >> 7;
    int ci = 16 * bp + col;
    floatx4 o;
#pragma unroll
    for (int r = 0; r < 4; r++) {
      int cj = 16 * ap + 4 * qd + r;
      int dc = cj - ci; if (dc < 0) dc = -dc;
      o[r] = biases[h * 1024 + dra * 32 + dc] * LOG2E;
    }
    *(floatx4*)&biast[(size_t)tile * 256 + lane * 4] = o;
  }
}

// ---------------- 128x128 tile GEMM, C = A @ Bt^T ------------------
// A [M][1024] bf16 row-major, Bt [N][1024] bf16 row-major (= B transposed).
// MODE 0: QKV epilogue (Q pre-scaled by SCLQ; q,k [bh][n][64], vt [bh][64][n])
// MODE 1: out-proj epilogue (add bvec, fp32 store)
template <int MODE>
__global__ __launch_bounds__(256, 2) void gemm_bt(
    const short* __restrict__ A, const short* __restrict__ Bt,
    short* __restrict__ qo, short* __restrict__ ko, short* __restrict__ vto,
    const float* __restrict__ bvec, float* __restrict__ outf) {
  __shared__ __align__(16) short sA[128 * 64];
  __shared__ __align__(16) short sB[128 * 64];
  const int tid = threadIdx.x;
  const int w = tid >> 6, lane = tid & 63;
  const int wr = w >> 1, wc = w & 1;
  const int bm = blockIdx.y, bn = blockIdx.x;
  const int qd = lane >> 4, col = lane & 15;

  floatx4 acc[4][4] = {};
  const int rowA0 = bm * 128, rowB0 = bn * 128;
  const int ciw = w * 256;

  for (int kk = 0; kk < 1024; kk += 64) {
    __syncthreads();
#pragma unroll
    for (int n = 0; n < 4; n++) {
      int ci = ciw + n * 64 + lane;
      int r = ci >> 3, c = (ci & 7) ^ (r & 7);
      gload_lds16(A + (size_t)(rowA0 + r) * 1024 + kk + c * 8, &sA[ci * 8]);
    }
#pragma unroll
    for (int n = 0; n < 4; n++) {
      int ci = ciw + n * 64 + lane;
      int r = ci >> 3, c = (ci & 7) ^ (r & 7);
      gload_lds16(Bt + (size_t)(rowB0 + r) * 1024 + kk + c * 8, &sB[ci * 8]);
    }
    __syncthreads();

#pragma unroll
    for (int ks = 0; ks < 2; ks++) {
      const int ch = qd + ks * 4;
      short8 af[4], bff[4];
#pragma unroll
      for (int rt = 0; rt < 4; rt++) {
        int r = wr * 64 + rt * 16 + col;
        af[rt] = *(const short8*)&sA[r * 64 + ((ch ^ (r & 7)) << 3)];
      }
#pragma unroll
      for (int ct = 0; ct < 4; ct++) {
        int r = wc * 64 + ct * 16 + col;
        bff[ct] = *(const short8*)&sB[r * 64 + ((ch ^ (r & 7)) << 3)];
      }
#pragma unroll
      for (int rt = 0; rt < 4; rt++)
#pragma unroll
        for (int ct = 0; ct < 4; ct++)
          acc[rt][ct] = __builtin_amdgcn_mfma_f32_16x16x32_bf16(af[rt], bff[ct], acc[rt][ct], 0, 0, 0);
    }
  }

  if (MODE == 0) {
    if (bn >= 16) {
      // V region (block-uniform): pack 4 consecutive n into b64 scatters
#pragma unroll
      for (int rt = 0; rt < 4; rt++) {
#pragma unroll
        for (int ct = 0; ct < 4; ct++) {
          int Cg = bn * 128 + wc * 64 + ct * 16 + col;
          int e = Cg & 1023, h = e >> 6, dd = e & 63;
          short4v pv;
#pragma unroll
          for (int r = 0; r < 4; r++) pv[r] = f2bf(acc[rt][ct][r]);
          int R0 = bm * 128 + wr * 64 + rt * 16 + qd * 4;
          int b = R0 >> 10, n0 = R0 & 1023;
          int bh = b * 16 + h;
          *(short4v*)&vto[((size_t)bh * 64 + dd) * 1024 + n0] = pv;
        }
      }
    } else {
      // Q (bn<8, pre-scaled by SCLQ) or K region; block-uniform choice
      short* dst = (bn < 8) ? qo : ko;
      const float qscl = (bn < 8) ? SCLQ : 1.0f;
#pragma unroll
      for (int rt = 0; rt < 4; rt++) {
#pragma unroll
        for (int ct = 0; ct < 4; ct++) {
          int Cg = bn * 128 + wc * 64 + ct * 16 + col;
          int e = Cg & 1023, h = e >> 6, dd = e & 63;
#pragma unroll
          for (int r = 0; r < 4; r++) {
            int R = bm * 128 + wr * 64 + rt * 16 + qd * 4 + r;
            int b = R >> 10, n = R & 1023;
            int bh = b * 16 + h;
            dst[((size_t)bh * 1024 + n) * 64 + dd] = f2bf(acc[rt][ct][r] * qscl);
          }
        }
      }
    }
  } else {
#pragma unroll
    for (int rt = 0; rt < 4; rt++)
#pragma unroll
      for (int ct = 0; ct < 4; ct++) {
        int Cg = bn * 128 + wc * 64 + ct * 16 + col;
        float bo = bvec[Cg];
#pragma unroll
        for (int r = 0; r < 4; r++) {
          int R = bm * 128 + wr * 64 + rt * 16 + qd * 4 + r;
          outf[(size_t)R * 1024 + Cg] = acc[rt][ct][r] + bo;
        }
      }
  }
}

// ---------------- fused attention (flash-style, no max: logits bounded) ----
// grid.x = bh (128), grid.y = qt (16). Per block: Q-tile 64 rows; 8 K/V tiles
// of 128. S^T = K Q'^T + bias (bias = MFMA C-init, f32; Q pre-scaled).
// K/V staged via VGPR prefetch + ds_write (no vmcnt drain at barriers);
// LDS: sK 16KB (XOR-8), sVt 16KB (XOR-16), sP 16KB (subchunk; Q temp).
// 48KB -> 3 blocks/CU. 3 barriers/js, all lgkm-only.
__global__ __launch_bounds__(256, 3) void attn_fused(
    const short* __restrict__ q, const short* __restrict__ k,
    const short* __restrict__ vt, const float* __restrict__ biast,
    short* __restrict__ ao) {
  __shared__ __align__(16) short sK[128 * 64];
  __shared__ __align__(16) short sVt[64 * 128];
  __shared__ __align__(16) short sP[64 * 128];
  const int tid = threadIdx.x, w = tid >> 6, lane = tid & 63;
  const int bh = blockIdx.x, qt = blockIdx.y;
  const int h = bh & 15;
  const int qd = lane >> 4, col = lane & 15;
  const short* qb = q + (size_t)bh * 65536;
  const short* kb = k + (size_t)bh * 65536;
  const short* vb = vt + (size_t)bh * 65536;
  const int ciw = w * 256;

  // per-thread staging geometry (js-invariant)
  int ldsi[4];          // LDS short index for both K and V commits
  const short* kp[4];   // K global src for js=0 (advance by 128*64/js)
  const short* vp[4];   // V global src for js=0 (advance by 128/js)
#pragma unroll
  for (int n = 0; n < 4; n++) {
    int ci = ciw + n * 64 + lane;
    ldsi[n] = ci * 8;
    int rk = ci >> 3, ck = (ci & 7) ^ (rk & 7);
    kp[n] = kb + (size_t)rk * 64 + ck * 8;
    int rv = ci >> 4, cv = (ci & 15) ^ (rv & 15);
    vp[n] = vb + (size_t)rv * 1024 + cv * 8;
  }

  // stage Q tile (64 rows at qt*64) into sP temp via DMA, and prefetch K0/V0
  // into registers (all drained by the one-time barrier below).
#pragma unroll
  for (int n = 0; n < 2; n++) {
    int ci = w * 128 + n * 64 + lane;
    int r = ci >> 3, c = (ci & 7) ^ (r & 7);
    gload_lds16(qb + (size_t)(qt * 64 + r) * 64 + c * 8, &sP[ci * 8]);
  }
  uint4v kreg[4], vreg[4];
#pragma unroll
  for (int n = 0; n < 4; n++) kreg[n] = *(const uint4v*)kp[n];
#pragma unroll
  for (int n = 0; n < 4; n++) vreg[n] = *(const uint4v*)vp[n];
  __syncthreads();
  short8 bq[2][4];  // [ks][ct] B-frags of Q, js-invariant (32 VGPRs)
#pragma unroll
  for (int ks = 0; ks < 2; ks++) {
    const int ch = qd + ks * 4;
#pragma unroll
    for (int ct = 0; ct < 4; ct++) {
      int r2 = ct * 16 + col;
      bq[ks][ct] = *(const short8*)&sP[r2 * 64 + ((ch ^ (r2 & 7)) << 3)];
    }
  }

  // ones B-frag for row-sum MFMA (bf16 1.0 = 0x3F80)
  short8 onesf;
#pragma unroll
  for (int t = 0; t < 8; t++) onesf[t] = (short)0x3F80;

  floatx4 oacc[4] = {};  // [d-tile ct], O rows i in [16w,16w+16)
  floatx4 osum = {};

  for (int js = 0; js < 8; js++) {
    __syncthreads();  // B1: prior PV/Q-frag LDS reads done (no vmem drain)
    // commit prefetched K/V regs -> LDS (contiguous b128, conflict-free)
#pragma unroll
    for (int n = 0; n < 4; n++) *(uint4v*)&sK[ldsi[n]] = kreg[n];
#pragma unroll
    for (int n = 0; n < 4; n++) *(uint4v*)&sVt[ldsi[n]] = vreg[n];
    // issue js+1 prefetch; stays in flight across B2/S/B3/PV
    if (js < 7) {
#pragma unroll
      for (int n = 0; n < 4; n++) kreg[n] = *(const uint4v*)(kp[n] + (size_t)(js + 1) * 8192);
#pragma unroll
      for (int n = 0; n < 4; n++) vreg[n] = *(const uint4v*)(vp[n] + (size_t)(js + 1) * 128);
    }
    __syncthreads();  // B2: LDS commits visible (lgkm-only drain)

    // S^T tiles (wave w: j rows [32w,32w+32), i cols 0..64): C-init = bias,
    // softmax = exp2 + pack only.
#pragma unroll
    for (int rt = 0; rt < 2; rt++) {
      const int a = js * 8 + w * 2 + rt;    // global j-tile
      const int s = w * 8 + rt * 4 + qd;    // P subchunk index (j>>2)
      const int ar = a >> 1, apar = a & 1;
      floatx4 sacc[4];
#pragma unroll
      for (int ct = 0; ct < 4; ct++) {      // C-init = f32 bias fragment
        int b = qt * 4 + ct;                 // global i-tile
        int dra = ar - (b >> 1); if (dra < 0) dra = -dra;
        int tile = ((h * 32 + dra) * 2 + apar) * 2 + (b & 1);
        sacc[ct] = *(const floatx4*)&biast[(size_t)tile * 256 + lane * 4];
      }
      const int r = w * 32 + rt * 16 + col;
      short8 ak0 = *(const short8*)&sK[r * 64 + (((qd + 0) ^ (r & 7)) << 3)];
      short8 ak1 = *(const short8*)&sK[r * 64 + (((qd + 4) ^ (r & 7)) << 3)];
#pragma unroll
      for (int ct = 0; ct < 4; ct++)
        sacc[ct] = __builtin_amdgcn_mfma_f32_16x16x32_bf16(ak0, bq[0][ct], sacc[ct], 0, 0, 0);
#pragma unroll
      for (int ct = 0; ct < 4; ct++)
        sacc[ct] = __builtin_amdgcn_mfma_f32_16x16x32_bf16(ak1, bq[1][ct], sacc[ct], 0, 0, 0);
#pragma unroll
      for (int ct = 0; ct < 4; ct++) {
        int i = ct * 16 + col;  // local i in [0,64)
        float e0 = fast_exp2(sacc[ct][0]);
        float e1 = fast_exp2(sacc[ct][1]);
        float e2 = fast_exp2(sacc[ct][2]);
        float e3 = fast_exp2(sacc[ct][3]);
        uint32_t u0 = __builtin_bit_cast(uint32_t, e0) + 0x8000u;
        uint32_t u1 = __builtin_bit_cast(uint32_t, e1) + 0x8000u;
        uint32_t u2 = __builtin_bit_cast(uint32_t, e2) + 0x8000u;
        uint32_t u3 = __builtin_bit_cast(uint32_t, e3) + 0x8000u;
        uint2v pk;
        pk.x = __builtin_amdgcn_perm(u1, u0, 0x07060302u);  // [bf(e1):bf(e0)]
        pk.y = __builtin_amdgcn_perm(u3, u2, 0x07060302u);  // [bf(e3):bf(e2)]
        *(uint2v*)&sP[i * 128 + ((s ^ (i & 15)) << 2)] = pk;  // conflict-free
      }
    }
    __syncthreads();  // B3: P visible cross-wave (lgkm-only)

    // O += P @ V ; osum += P @ 1. Wave w: O rows i in [16w,16w+16).
#pragma unroll
    for (int ks = 0; ks < 4; ks++) {
      const int ch = ks * 4 + qd;
      int m = w * 16 + col;
      short4v lo = *(const short4v*)&sP[m * 128 + (((2 * ch) ^ col) << 2)];
      short4v hi = *(const short4v*)&sP[m * 128 + (((2 * ch + 1) ^ col) << 2)];
      short8 ap = __builtin_shufflevector(lo, hi, 0, 1, 2, 3, 4, 5, 6, 7);
      short8 bv[4];
#pragma unroll
      for (int ct = 0; ct < 4; ct++) {
        int d = ct * 16 + col;
        bv[ct] = *(const short8*)&sVt[d * 128 + ((ch ^ (d & 15)) << 3)];
      }
#pragma unroll
      for (int ct = 0; ct < 4; ct++)
        oacc[ct] = __builtin_amdgcn_mfma_f32_16x16x32_bf16(ap, bv[ct], oacc[ct], 0, 0, 0);
      osum = __builtin_amdgcn_mfma_f32_16x16x32_bf16(ap, onesf, osum, 0, 0, 0);
    }
  }

  // write O as attn_out [b][n][h*64+dd] bf16 ; denominator from osum
  const int b = bh >> 4;
  floatx4 inv;
#pragma unroll
  for (int r = 0; r < 4; r++) inv[r] = 1.0f / osum[r];
#pragma unroll
  for (int ct = 0; ct < 4; ct++)
#pragma unroll
    for (int r = 0; r < 4; r++) {
      int n = qt * 64 + w * 16 + qd * 4 + r;
      int dd = ct * 16 + col;
      ao[(((size_t)b * 1024 + n) << 10) + h * 64 + dd] = f2bf(oacc[ct][r] * inv[r]);
    }
}

// -------------------------------------------------------------------
extern "C" void kernel_launch(void* const* d_in, const int* in_sizes, int n_in,
                              void* d_out, int out_size, void* d_ws, size_t ws_size,
                              hipStream_t stream) {
  const float* x = (const float*)d_in[0];       // [8,1024,1024]
  const float* w_qkv = (const float*)d_in[1];   // [3072,1024]
  const float* biases = (const float*)d_in[2];  // [16,1024]
  // d_in[3] bias_idxs unused: index formula is closed-form
  const float* w_out = (const float*)d_in[4];   // [1024,1024]
  const float* b_out = (const float*)d_in[5];   // [1024]
  float* out = (float*)d_out;

  char* ws = (char*)d_ws;
  short* xb    = (short*)(ws + 0);          // 16 MB  [8192][1024]
  short* wqkvb = (short*)(ws + 16777216);   // 6 MB   [3072][1024]
  short* woutb = (short*)(ws + 23068672);   // 2 MB   [1024][1024]
  short* qb    = (short*)(ws + 25165824);   // 16 MB  [128 bh][1024][64]
  short* kb    = (short*)(ws + 41943040);   // 16 MB
  short* vtb   = (short*)(ws + 58720256);   // 16 MB  [128 bh][64][1024]
  short* aob   = (short*)(ws + 75497472);   // 16 MB  [8192][1024]
  float* biast = (float*)(ws + 92274688);   // 2 MB   [16][32][2][2][64][4] f32

  prep<<<13312, 256, 0, stream>>>(x, w_qkv, w_out, biases, xb, wqkvb, woutb, biast);
  gemm_bt<0><<<dim3(24, 64), 256, 0, stream>>>(xb, wqkvb, qb, kb, vtb, nullptr, nullptr);
  attn_fused<<<dim3(128, 16), 256, 0, stream>>>(qb, kb, vtb, biast, aob);
  gemm_bt<1><<<dim3(8, 64), 256, 0, stream>>>(aob, woutb, nullptr, nullptr, nullptr, b_out, out);
}